// Round 2
// baseline (352.628 us; speedup 1.0000x reference)
//
#include <hip/hip_runtime.h>
#include <hip/hip_bf16.h>

// ---------------------------------------------------------------------------
// CosineGraphAttentionLayer: O = softmax(beta*cos(xi,xj) + mask(adj)) @ xj
// N=M=8192, D=256, f32 in/out.
//
// Strategy: fold beta/row-norms into f16 copies (scores |s|<1 -> no online
// max needed; masked softmax = linear num/den accumulation, split over j).
// Swapped QK^T (mfma(xj_s, xi_s) -> S^T) so P lives per-lane with i=lane&31;
// PV A-operand built in-register (cvt_pkrtz + shfl_xor(32)). V^T staged to
// LDS via global_load_lds from a pre-swizzled global transpose (chunk^=d&15)
// so PV ds_read_b128 is bank-conflict-free.
// ---------------------------------------------------------------------------

typedef _Float16 half8  __attribute__((ext_vector_type(8)));
typedef _Float16 half4v __attribute__((ext_vector_type(4)));
typedef __fp16   fp16x2 __attribute__((ext_vector_type(2)));
typedef float    f32x16 __attribute__((ext_vector_type(16)));
typedef int      i32x4  __attribute__((ext_vector_type(4)));

#define GAS __attribute__((address_space(1)))
#define LAS __attribute__((address_space(3)))

#define N_ROWS 8192
#define M_ROWS 8192
#define DDIM   256

// ---- prep: row L2 norm, scale, convert to f16 ------------------------------
// use_beta=1: out = x * beta/||x||  (xi);  use_beta=0: out = x/||x||  (xj)
__global__ void prep_scale(const float* __restrict__ x, _Float16* __restrict__ xs,
                           const float* __restrict__ betap, int use_beta) {
    int row  = blockIdx.x * 4 + (threadIdx.x >> 6);
    int lane = threadIdx.x & 63;
    const float4 v = *(const float4*)(x + (size_t)row * DDIM + lane * 4);
    float ss = v.x * v.x + v.y * v.y + v.z * v.z + v.w * v.w;
#pragma unroll
    for (int o = 32; o > 0; o >>= 1) ss += __shfl_xor(ss, o, 64);
    float sc = (use_beta ? betap[0] : 1.0f) / sqrtf(ss);
    half4v hv = {(_Float16)(v.x * sc), (_Float16)(v.y * sc),
                 (_Float16)(v.z * sc), (_Float16)(v.w * sc)};
    *(half4v*)(xs + (size_t)row * DDIM + lane * 4) = hv;
}

// ---- prep: xjT[d][j] = f16(xj[j][d]), stored with 16B-chunk swizzle --------
// Within each 256B-aligned group of 16 chunks (128 j), global chunk c holds
// plain chunk (c ^ (d&15)).  Matches the LDS read-side XOR in the main kernel.
__global__ void prep_transpose(const float* __restrict__ xj, _Float16* __restrict__ xjT) {
    __shared__ _Float16 ldsT[256][128];  // 64KB
    const int t = threadIdx.x;
    const int jbase = blockIdx.x * 128;
#pragma unroll 4
    for (int it = 0; it < 32; ++it) {
        int d4   = t & 63;              // float4 index over D
        int jloc = (t >> 6) + it * 4;   // 0..127
        float4 v = *(const float4*)(xj + (size_t)(jbase + jloc) * DDIM + d4 * 4);
        ldsT[d4 * 4 + 0][jloc] = (_Float16)v.x;
        ldsT[d4 * 4 + 1][jloc] = (_Float16)v.y;
        ldsT[d4 * 4 + 2][jloc] = (_Float16)v.z;
        ldsT[d4 * 4 + 3][jloc] = (_Float16)v.w;
    }
    __syncthreads();
    for (int it = 0; it < 16; ++it) {
        int d = it * 16 + (t >> 4);
        int c = t & 15;
        int csrc = c ^ (d & 15);
        i32x4 val = *(const i32x4*)&ldsT[d][csrc * 8];
        *(i32x4*)((char*)xjT + (size_t)d * (M_ROWS * 2) + (size_t)jbase * 2 + c * 16) = val;
    }
}

// ---- main fused kernel -----------------------------------------------------
// grid (256, 2): blockIdx.x -> 32-row i-tile; blockIdx.y -> j half (4096 j).
// 4 waves; wave w owns j sub-range [w*32, w*32+32) of each 128-wide j-tile.
__global__ __launch_bounds__(256, 2)
void attn_main(const _Float16* __restrict__ xi_s, const _Float16* __restrict__ xj_s,
               const _Float16* __restrict__ xjT, const int* __restrict__ adj,
               float* __restrict__ out, float* __restrict__ den) {
    __shared__ char ldsraw[65536];  // V^T tile [256 d][128 j] f16, swizzled
    const int tid  = threadIdx.x;
    const int w    = tid >> 6;
    const int lane = tid & 63;
    const int il   = lane & 31;   // i-local (QK^T) / d-local (PV output col)
    const int h    = lane >> 5;   // half-wave
    const int ibase = blockIdx.x * 32;
    const int jh    = blockIdx.y;

    // preload xi fragments (B-operand of swapped QK^T): row ibase+il, all K
    half8 bq[16];
#pragma unroll
    for (int kt = 0; kt < 16; ++kt)
        bq[kt] = *(const half8*)(xi_s + (size_t)(ibase + il) * DDIM + kt * 16 + h * 8);

    f32x16 acc[8];
#pragma unroll
    for (int f = 0; f < 8; ++f)
#pragma unroll
        for (int r = 0; r < 16; ++r) acc[f][r] = 0.f;
    float rden = 0.f;

    for (int jt = 0; jt < 32; ++jt) {
        const int jbase0  = jh * 4096 + jt * 128;
        const int jb_wave = jbase0 + w * 32;
        __syncthreads();  // prev PV reads done before overwriting LDS
        // stage V^T tile (64KB): linear LDS dest, pre-swizzled global source
        {
            const char* gb = (const char*)xjT;
#pragma unroll
            for (int it = 0; it < 16; ++it) {
                int d = it * 16 + w * 4 + (lane >> 4);
                const char* gp = gb + (size_t)d * (M_ROWS * 2) + (size_t)jbase0 * 2 + (lane & 15) * 16;
                __builtin_amdgcn_global_load_lds((const GAS unsigned int*)gp,
                                                 (LAS unsigned int*)(ldsraw + it * 4096 + w * 1024),
                                                 16, 0, 0);
            }
        }
        // QK^T (swapped): S^T[j][i] ; A = xj_s rows (j), B = xi_s regs (i)
        f32x16 sacc;
#pragma unroll
        for (int r = 0; r < 16; ++r) sacc[r] = 0.f;
#pragma unroll
        for (int kt = 0; kt < 16; ++kt) {
            half8 afr = *(const half8*)(xj_s + (size_t)(jb_wave + il) * DDIM + kt * 16 + h * 8);
            sacc = __builtin_amdgcn_mfma_f32_32x32x16_f16(afr, bq[kt], sacc, 0, 0, 0);
        }
        // lane holds S^T[jrow(r)][il]: jrow = (r&3) + 8*(r>>2) + 4h
        const int* adjrow = adj + (size_t)(ibase + il) * M_ROWS + jb_wave + 4 * h;
        i32x4 av[4];
#pragma unroll
        for (int g = 0; g < 4; ++g) av[g] = *(const i32x4*)(adjrow + 8 * g);
        float wv[16];
#pragma unroll
        for (int r = 0; r < 16; ++r) {
            float e = av[r >> 2][r & 3] ? __expf(sacc[r]) : 0.f;  // |s|<1, no max needed
            wv[r] = e;
            rden += e;
        }
        // build PV A-fragments in-register (T12 structure)
        int pq[8], qq[8];
#pragma unroll
        for (int q = 0; q < 8; ++q) {
            fp16x2 pp = __builtin_amdgcn_cvt_pkrtz(wv[2 * q], wv[2 * q + 1]);
            pq[q] = __builtin_bit_cast(int, pp);
            qq[q] = __shfl_xor(pq[q], 32, 64);
        }
        i32x4 af0 = {h ? qq[2] : pq[0], h ? qq[3] : pq[1], h ? pq[2] : qq[0], h ? pq[3] : qq[1]};
        i32x4 af1 = {h ? qq[6] : pq[4], h ? qq[7] : pq[5], h ? pq[6] : qq[4], h ? pq[7] : qq[5]};
        half8 afA = __builtin_bit_cast(half8, af0);
        half8 afB = __builtin_bit_cast(half8, af1);
        asm volatile("s_waitcnt vmcnt(0)" ::: "memory");
        __syncthreads();  // V^T tile staged
        // PV: O_partial[i][d] += W[i][j] * V[j][d]  (k = wave's 32 j)
#pragma unroll
        for (int f = 0; f < 8; ++f) {
            const int rowoff = (f * 32 + il) * 256;
            {
                int cp = w * 4 + h;
                half8 bfr = *(const half8*)(ldsraw + rowoff + ((cp ^ (il & 15)) << 4));
                acc[f] = __builtin_amdgcn_mfma_f32_32x32x16_f16(afA, bfr, acc[f], 0, 0, 0);
            }
            {
                int cp = w * 4 + 2 + h;
                half8 bfr = *(const half8*)(ldsraw + rowoff + ((cp ^ (il & 15)) << 4));
                acc[f] = __builtin_amdgcn_mfma_f32_32x32x16_f16(afB, bfr, acc[f], 0, 0, 0);
            }
        }
    }
    // den: reduce across half-waves, then global atomic
    rden += __shfl_xor(rden, 32, 64);
    if (lane < 32) atomicAdd(&den[ibase + lane], rden);
    // merge partial O across the 4 waves via LDS, then one atomicAdd pass
    __syncthreads();
    float* ldsO = (float*)ldsraw;
#pragma unroll
    for (int k = 0; k < 32; ++k) ldsO[tid + k * 256] = 0.f;
    __syncthreads();
#pragma unroll
    for (int f = 0; f < 8; ++f) {
#pragma unroll
        for (int r = 0; r < 16; ++r) {
            int irow = (r & 3) + 8 * (r >> 2) + 4 * h;
            atomicAdd(&ldsO[irow * 256 + f * 32 + il], acc[f][r]);
        }
    }
    __syncthreads();
    float* op = out + (size_t)ibase * DDIM;
    for (int k = 0; k < 32; ++k) {
        int e = tid + k * 256;
        atomicAdd(&op[e], ldsO[e]);
    }
}

// ---- finalize: O[i][:] /= den[i] ------------------------------------------
__global__ void finalize_div(float* __restrict__ out, const float* __restrict__ den) {
    int row = blockIdx.x;
    out[(size_t)row * DDIM + threadIdx.x] /= den[row];
}

extern "C" void kernel_launch(void* const* d_in, const int* in_sizes, int n_in,
                              void* d_out, int out_size, void* d_ws, size_t ws_size,
                              hipStream_t stream) {
    const float* xi   = (const float*)d_in[0];
    const float* xj   = (const float*)d_in[1];
    const int*   adj  = (const int*)d_in[2];
    const float* beta = (const float*)d_in[3];
    float* out = (float*)d_out;
    char*  ws  = (char*)d_ws;

    _Float16* xi_s = (_Float16*)(ws);                    // 4MB
    _Float16* xj_s = (_Float16*)(ws + (4u << 20));       // 4MB
    _Float16* xjT  = (_Float16*)(ws + (8u << 20));       // 4MB (swizzled transpose)
    float*    den  = (float*)(ws + (12u << 20));         // 32KB

    hipMemsetAsync(d_out, 0, (size_t)N_ROWS * DDIM * sizeof(float), stream);
    hipMemsetAsync(den, 0, (size_t)N_ROWS * sizeof(float), stream);

    prep_scale<<<N_ROWS / 4, 256, 0, stream>>>(xi, xi_s, beta, 1);
    prep_scale<<<M_ROWS / 4, 256, 0, stream>>>(xj, xj_s, beta, 0);
    prep_transpose<<<M_ROWS / 128, 256, 0, stream>>>(xj, xjT);
    attn_main<<<dim3(256, 2), 256, 0, stream>>>(xi_s, xj_s, xjT, adj, out, den);
    finalize_div<<<N_ROWS, 256, 0, stream>>>(out, den);
}

// Round 4
// 303.794 us; speedup vs baseline: 1.1607x; 1.1607x over previous
//
#include <hip/hip_runtime.h>
#include <hip/hip_bf16.h>

// ---------------------------------------------------------------------------
// CosineGraphAttentionLayer: O = softmax(beta*cos(xi,xj) + mask(adj)) @ xj
// N=M=8192, D=256, f32 in/out.
//
// R4 = R3 structure (barrier-free main loop, fragment-major global operands)
// with the prep bug fixed: xjA (QK^T operand) from NORMALIZED xj, xjF (PV
// V-operand) from RAW xj (output is P @ xj, not P @ x-hat).
// ---------------------------------------------------------------------------

typedef _Float16 half8  __attribute__((ext_vector_type(8)));
typedef _Float16 half4v __attribute__((ext_vector_type(4)));
typedef __fp16   fp16x2 __attribute__((ext_vector_type(2)));
typedef float    f32x16 __attribute__((ext_vector_type(16)));
typedef int      i32x4  __attribute__((ext_vector_type(4)));

#define N_ROWS 8192
#define M_ROWS 8192
#define DDIM   256

// ---- prep: xi * beta/||xi|| -> f16 ----------------------------------------
__global__ void prep_scale(const float* __restrict__ x, _Float16* __restrict__ xs,
                           const float* __restrict__ betap) {
    int row  = blockIdx.x * 4 + (threadIdx.x >> 6);
    int lane = threadIdx.x & 63;
    const float4 v = *(const float4*)(x + (size_t)row * DDIM + lane * 4);
    float ss = v.x * v.x + v.y * v.y + v.z * v.z + v.w * v.w;
#pragma unroll
    for (int o = 32; o > 0; o >>= 1) ss += __shfl_xor(ss, o, 64);
    float sc = betap[0] / sqrtf(ss);
    half4v hv = {(_Float16)(v.x * sc), (_Float16)(v.y * sc),
                 (_Float16)(v.z * sc), (_Float16)(v.w * sc)};
    *(half4v*)(xs + (size_t)row * DDIM + lane * 4) = hv;
}

// ---- prep: xj -> fragment-major xjA (normalized, QK^T A) and xjF (raw, PV B)
// One block per 32-j block (256 blocks).
// xjA entry [(jb*16 + kt)*64 + l]: xjn[jb*32 + (l&31)][kt*16 + (l>>5)*8 ..+8]
// xjF entry [(jb*16 + f*2 + s)*64 + l]: raw V^T, d=f*32+(l&31),
//            j = jb*32 + s*16 + (l>>5)*8 ..+8
__global__ void prep_xj(const float* __restrict__ xj, half8* __restrict__ xjA,
                        half8* __restrict__ xjF) {
    __shared__ _Float16 tileR[32][272];  // raw f16
    __shared__ _Float16 tileN[32][272];  // normalized f16
    __shared__ float red[32][8];
    __shared__ float rsc[32];
    const int t  = threadIdx.x;
    const int jb = blockIdx.x;           // 0..255
    const int row = t >> 3, seg = t & 7;
    const float* src = xj + (size_t)(jb * 32 + row) * DDIM + seg * 32;
    float4 v[8];
    float ss = 0.f;
#pragma unroll
    for (int q = 0; q < 8; ++q) {
        v[q] = ((const float4*)src)[q];
        ss += v[q].x * v[q].x + v[q].y * v[q].y + v[q].z * v[q].z + v[q].w * v[q].w;
    }
    red[row][seg] = ss;
    __syncthreads();
    if (t < 32) {
        float s = 0.f;
#pragma unroll
        for (int q = 0; q < 8; ++q) s += red[t][q];
        rsc[t] = 1.0f / sqrtf(s);
    }
    __syncthreads();
    const float sc = rsc[row];
#pragma unroll
    for (int q = 0; q < 8; ++q) {
        int c = seg * 32 + q * 4;
        tileR[row][c + 0] = (_Float16)v[q].x;
        tileR[row][c + 1] = (_Float16)v[q].y;
        tileR[row][c + 2] = (_Float16)v[q].z;
        tileR[row][c + 3] = (_Float16)v[q].w;
        tileN[row][c + 0] = (_Float16)(v[q].x * sc);
        tileN[row][c + 1] = (_Float16)(v[q].y * sc);
        tileN[row][c + 2] = (_Float16)(v[q].z * sc);
        tileN[row][c + 3] = (_Float16)(v[q].w * sc);
    }
    __syncthreads();
#pragma unroll
    for (int rep = 0; rep < 4; ++rep) {
        int idx = t + rep * 256;               // 0..1023
        int kt = idx >> 6, l = idx & 63, il = l & 31, hh = l >> 5;
        half8 val = *(const half8*)&tileN[il][kt * 16 + hh * 8];
        xjA[((size_t)jb * 16 + kt) * 64 + l] = val;
    }
#pragma unroll
    for (int rep = 0; rep < 4; ++rep) {
        int idx = t + rep * 256;               // 0..1023
        int f = idx >> 7, s = (idx >> 6) & 1, l = idx & 63, il = l & 31, hh = l >> 5;
        int d = f * 32 + il, jl = s * 16 + hh * 8;
        half8 val;
#pragma unroll
        for (int e = 0; e < 8; ++e) val[e] = tileR[jl + e][d];
        xjF[((size_t)jb * 16 + f * 2 + s) * 64 + l] = val;
    }
}

// ---- main fused kernel (barrier-free inner loop) ---------------------------
// grid (256, 2): blockIdx.x -> 32-row i-tile; blockIdx.y -> j half (4096 j).
// 4 waves; wave w owns j-blocks jb32 = jh*128 + jt*4 + w, jt = 0..31.
__global__ __launch_bounds__(256, 2)
void attn_main(const _Float16* __restrict__ xi_s, const half8* __restrict__ xjA,
               const half8* __restrict__ xjF, const int* __restrict__ adj,
               float* __restrict__ out, float* __restrict__ den) {
    __shared__ float ldsO[32 * 256];   // 32KB merge buffer
    const int tid  = threadIdx.x;
    const int w    = tid >> 6;
    const int lane = tid & 63;
    const int il   = lane & 31;
    const int h    = lane >> 5;
    const int ibase = blockIdx.x * 32;
    const int jh    = blockIdx.y;

    // xi fragments (B-operand of swapped QK^T)
    half8 bq[16];
#pragma unroll
    for (int kt = 0; kt < 16; ++kt)
        bq[kt] = *(const half8*)(xi_s + (size_t)(ibase + il) * DDIM + kt * 16 + h * 8);

    f32x16 acc[8];
#pragma unroll
    for (int f = 0; f < 8; ++f)
#pragma unroll
        for (int r = 0; r < 16; ++r) acc[f][r] = 0.f;
    float rden = 0.f;

    // per-lane adj row pointer (wave's 32-j window at tile jt starts +jt*128)
    const int* arow = adj + (size_t)(ibase + il) * M_ROWS + jh * (M_ROWS / 2) + w * 32 + 4 * h;
    const half8* aBase = xjA + (size_t)jh * 128 * 16 * 64;
    const half8* fBase = xjF + (size_t)jh * 128 * 16 * 64;

    i32x4 av[4];
#pragma unroll
    for (int g = 0; g < 4; ++g)
        av[g] = __builtin_nontemporal_load((const i32x4*)(arow + 8 * g));

    for (int jt = 0; jt < 32; ++jt) {
        // prefetch next tile's adj (wraps to 0 on last iter; harmless re-read)
        const int jn = (jt + 1) & 31;
        i32x4 nv[4];
#pragma unroll
        for (int g = 0; g < 4; ++g)
            nv[g] = __builtin_nontemporal_load((const i32x4*)(arow + jn * 128 + 8 * g));

        // QK^T (swapped): S^T[j][i]; A-frags coalesced from xjA
        const half8* ap = aBase + ((size_t)(jt * 4 + w) * 16) * 64 + lane;
        f32x16 sacc;
#pragma unroll
        for (int r = 0; r < 16; ++r) sacc[r] = 0.f;
#pragma unroll
        for (int kt = 0; kt < 16; ++kt)
            sacc = __builtin_amdgcn_mfma_f32_32x32x16_f16(ap[kt * 64], bq[kt], sacc, 0, 0, 0);

        // masked exp; |s|<1 so no max tracking
        float wv[16];
#pragma unroll
        for (int r = 0; r < 16; ++r) {
            float e = av[r >> 2][r & 3] ? __expf(sacc[r]) : 0.f;
            wv[r] = e;
            rden += e;
        }
        // pack W to f16 PV A-frags in-register
        int pq[8], qq[8];
#pragma unroll
        for (int q = 0; q < 8; ++q) {
            fp16x2 pp = __builtin_amdgcn_cvt_pkrtz(wv[2 * q], wv[2 * q + 1]);
            pq[q] = __builtin_bit_cast(int, pp);
            qq[q] = __shfl_xor(pq[q], 32, 64);
        }
        i32x4 af0 = {h ? qq[2] : pq[0], h ? qq[3] : pq[1], h ? pq[2] : qq[0], h ? pq[3] : qq[1]};
        i32x4 af1 = {h ? qq[6] : pq[4], h ? qq[7] : pq[5], h ? pq[6] : qq[4], h ? pq[7] : qq[5]};
        half8 afA = __builtin_bit_cast(half8, af0);
        half8 afB = __builtin_bit_cast(half8, af1);

        // PV: O[i][d] += W[i][j] * V[j][d]; B-frags coalesced from xjF
        const half8* fp_ = fBase + ((size_t)(jt * 4 + w) * 16) * 64 + lane;
#pragma unroll
        for (int f = 0; f < 8; ++f) {
            acc[f] = __builtin_amdgcn_mfma_f32_32x32x16_f16(afA, fp_[(f * 2 + 0) * 64], acc[f], 0, 0, 0);
            acc[f] = __builtin_amdgcn_mfma_f32_32x32x16_f16(afB, fp_[(f * 2 + 1) * 64], acc[f], 0, 0, 0);
        }
#pragma unroll
        for (int g = 0; g < 4; ++g) av[g] = nv[g];
    }

    // den: reduce across half-waves, then global atomic
    rden += __shfl_xor(rden, 32, 64);
    if (lane < 32) atomicAdd(&den[ibase + lane], rden);

    // merge partial O across the 4 waves via LDS, then one atomicAdd pass
    __syncthreads();
#pragma unroll
    for (int k = 0; k < 32; ++k) ldsO[tid + k * 256] = 0.f;
    __syncthreads();
#pragma unroll
    for (int f = 0; f < 8; ++f) {
#pragma unroll
        for (int r = 0; r < 16; ++r) {
            int irow = (r & 3) + 8 * (r >> 2) + 4 * h;
            atomicAdd(&ldsO[irow * 256 + f * 32 + il], acc[f][r]);
        }
    }
    __syncthreads();
    float* op = out + (size_t)ibase * DDIM;
    for (int k = 0; k < 32; ++k) {
        int e = tid + k * 256;
        atomicAdd(&op[e], ldsO[e]);
    }
}

// ---- finalize: O[i][:] /= den[i] ------------------------------------------
__global__ void finalize_div(float* __restrict__ out, const float* __restrict__ den) {
    int row = blockIdx.x;
    out[(size_t)row * DDIM + threadIdx.x] /= den[row];
}

extern "C" void kernel_launch(void* const* d_in, const int* in_sizes, int n_in,
                              void* d_out, int out_size, void* d_ws, size_t ws_size,
                              hipStream_t stream) {
    const float* xi   = (const float*)d_in[0];
    const float* xj   = (const float*)d_in[1];
    const int*   adj  = (const int*)d_in[2];
    const float* beta = (const float*)d_in[3];
    float* out = (float*)d_out;
    char*  ws  = (char*)d_ws;

    _Float16* xi_s = (_Float16*)(ws);                // 4MB
    half8*    xjA  = (half8*)(ws + (4u << 20));      // 4MB
    half8*    xjF  = (half8*)(ws + (8u << 20));      // 4MB
    float*    den  = (float*)(ws + (12u << 20));     // 32KB

    hipMemsetAsync(d_out, 0, (size_t)N_ROWS * DDIM * sizeof(float), stream);
    hipMemsetAsync(den, 0, (size_t)N_ROWS * sizeof(float), stream);

    prep_scale<<<N_ROWS / 4, 256, 0, stream>>>(xi, xi_s, beta);
    prep_xj<<<M_ROWS / 32, 256, 0, stream>>>(xj, xjA, xjF);
    attn_main<<<dim3(256, 2), 256, 0, stream>>>(xi_s, xjA, xjF, adj, out, den);
    finalize_div<<<N_ROWS, 256, 0, stream>>>(out, den);
}

// Round 5
// 180.896 us; speedup vs baseline: 1.9493x; 1.6794x over previous
//
#include <hip/hip_runtime.h>
#include <hip/hip_bf16.h>

// ---------------------------------------------------------------------------
// CosineGraphAttentionLayer: O = softmax(beta*cos(xi,xj) + mask(adj)) @ xj
// N=M=8192, D=256, f32 in/out.
//
// R5: BM=128 (8 waves), j-tile=64, double-buffered LDS staging of frag-major
// xjA/xjF via global_load_lds (zero VGPR prefetch), d-split PV (acc=64 AGPR)
// with W-fragment exchange through LDS, XCD-swizzled work map (per-XCD
// j-quarter -> 2MB L2-resident xj working set). adj nontemporal, prefetched
// one tile ahead. Numerics identical to validated R4.
// ---------------------------------------------------------------------------

typedef _Float16 half8  __attribute__((ext_vector_type(8)));
typedef _Float16 half4v __attribute__((ext_vector_type(4)));
typedef __fp16   fp16x2 __attribute__((ext_vector_type(2)));
typedef float    f32x16 __attribute__((ext_vector_type(16)));
typedef int      i32x4  __attribute__((ext_vector_type(4)));

#define GAS __attribute__((address_space(1)))
#define LAS __attribute__((address_space(3)))

#define N_ROWS 8192
#define M_ROWS 8192
#define DDIM   256

// ---- prep: xi * beta/||xi|| -> f16 (validated R4) --------------------------
__global__ void prep_scale(const float* __restrict__ x, _Float16* __restrict__ xs,
                           const float* __restrict__ betap) {
    int row  = blockIdx.x * 4 + (threadIdx.x >> 6);
    int lane = threadIdx.x & 63;
    const float4 v = *(const float4*)(x + (size_t)row * DDIM + lane * 4);
    float ss = v.x * v.x + v.y * v.y + v.z * v.z + v.w * v.w;
#pragma unroll
    for (int o = 32; o > 0; o >>= 1) ss += __shfl_xor(ss, o, 64);
    float sc = betap[0] / sqrtf(ss);
    half4v hv = {(_Float16)(v.x * sc), (_Float16)(v.y * sc),
                 (_Float16)(v.z * sc), (_Float16)(v.w * sc)};
    *(half4v*)(xs + (size_t)row * DDIM + lane * 4) = hv;
}

// ---- prep: xj -> frag-major xjA (normalized) / xjF (raw) (validated R4) ----
__global__ void prep_xj(const float* __restrict__ xj, half8* __restrict__ xjA,
                        half8* __restrict__ xjF) {
    __shared__ _Float16 tileR[32][272];
    __shared__ _Float16 tileN[32][272];
    __shared__ float red[32][8];
    __shared__ float rsc[32];
    const int t  = threadIdx.x;
    const int jb = blockIdx.x;
    const int row = t >> 3, seg = t & 7;
    const float* src = xj + (size_t)(jb * 32 + row) * DDIM + seg * 32;
    float4 v[8];
    float ss = 0.f;
#pragma unroll
    for (int q = 0; q < 8; ++q) {
        v[q] = ((const float4*)src)[q];
        ss += v[q].x * v[q].x + v[q].y * v[q].y + v[q].z * v[q].z + v[q].w * v[q].w;
    }
    red[row][seg] = ss;
    __syncthreads();
    if (t < 32) {
        float s = 0.f;
#pragma unroll
        for (int q = 0; q < 8; ++q) s += red[t][q];
        rsc[t] = 1.0f / sqrtf(s);
    }
    __syncthreads();
    const float sc = rsc[row];
#pragma unroll
    for (int q = 0; q < 8; ++q) {
        int c = seg * 32 + q * 4;
        tileR[row][c + 0] = (_Float16)v[q].x;
        tileR[row][c + 1] = (_Float16)v[q].y;
        tileR[row][c + 2] = (_Float16)v[q].z;
        tileR[row][c + 3] = (_Float16)v[q].w;
        tileN[row][c + 0] = (_Float16)(v[q].x * sc);
        tileN[row][c + 1] = (_Float16)(v[q].y * sc);
        tileN[row][c + 2] = (_Float16)(v[q].z * sc);
        tileN[row][c + 3] = (_Float16)(v[q].w * sc);
    }
    __syncthreads();
#pragma unroll
    for (int rep = 0; rep < 4; ++rep) {
        int idx = t + rep * 256;
        int kt = idx >> 6, l = idx & 63, il = l & 31, hh = l >> 5;
        half8 val = *(const half8*)&tileN[il][kt * 16 + hh * 8];
        xjA[((size_t)jb * 16 + kt) * 64 + l] = val;
    }
#pragma unroll
    for (int rep = 0; rep < 4; ++rep) {
        int idx = t + rep * 256;
        int f = idx >> 7, s = (idx >> 6) & 1, l = idx & 63, il = l & 31, hh = l >> 5;
        int d = f * 32 + il, jl = s * 16 + hh * 8;
        half8 val;
#pragma unroll
        for (int e = 0; e < 8; ++e) val[e] = tileR[jl + e][d];
        xjF[((size_t)jb * 16 + f * 2 + s) * 64 + l] = val;
    }
}

// ---- main fused kernel -----------------------------------------------------
// 256 blocks x 512 threads. Work remap: wid=(bid%8)*32+bid/8; jq=wid>>6 (2048-j
// quarter), itile=wid&63 (128-i tile). Wave w: iq=w>>1 (32-i sub), js=w&1
// (32-j sub of 64-j tile + 128-d half for PV). 32 tiles of 64 j.
// LDS: buf c @ c*65536 {A 32KB | F 32KB}; wlds @ 131072 (16KB). Total 144KB.
__global__ __launch_bounds__(512, 1)
void attn_main(const _Float16* __restrict__ xi_s, const half8* __restrict__ xjA,
               const half8* __restrict__ xjF, const int* __restrict__ adj,
               float* __restrict__ out, float* __restrict__ den) {
    extern __shared__ char lds[];
    const int tid  = threadIdx.x;
    const int w    = tid >> 6;
    const int lane = tid & 63;
    const int il   = lane & 31;
    const int h    = lane >> 5;
    const int iq   = w >> 1;
    const int js   = w & 1;

    const int bid   = blockIdx.x;
    const int wid   = (bid & 7) * 32 + (bid >> 3);
    const int jq    = wid >> 6;
    const int itile = wid & 63;
    const int ibase = itile * 128;
    const int irow  = ibase + iq * 32 + il;

    // xi B-operand frags
    half8 bq[16];
#pragma unroll
    for (int kt = 0; kt < 16; ++kt)
        bq[kt] = *(const half8*)(xi_s + (size_t)irow * DDIM + kt * 16 + h * 8);

    f32x16 acc[4];
#pragma unroll
    for (int f = 0; f < 4; ++f)
#pragma unroll
        for (int r = 0; r < 16; ++r) acc[f][r] = 0.f;
    float rden = 0.f;

    const int* arow = adj + (size_t)irow * M_ROWS + jq * 2048 + js * 32 + 4 * h;
    const char* gA = (const char*)xjA;
    const char* gF = (const char*)xjF;
    const size_t qoff = (size_t)(jq * 64) * 16384;  // quarter start, bytes

    // ---- staging helper (8 x global_load_lds, 16B each, frag-major linear)
#define STAGE(T, B)                                                             \
    {                                                                           \
        const size_t go = qoff + (size_t)(T) * 32768;                           \
        const int lo = (B) * 65536 + w * 1024 + (lane << 4);                    \
        _Pragma("unroll")                                                       \
        for (int k = 0; k < 4; ++k)                                             \
            __builtin_amdgcn_global_load_lds(                                   \
                (const GAS unsigned int*)(gA + go + k * 8192 + w * 1024 + (lane << 4)), \
                (LAS unsigned int*)(lds + lo + k * 8192), 16, 0, 0);            \
        _Pragma("unroll")                                                       \
        for (int k = 0; k < 4; ++k)                                             \
            __builtin_amdgcn_global_load_lds(                                   \
                (const GAS unsigned int*)(gF + go + k * 8192 + w * 1024 + (lane << 4)), \
                (LAS unsigned int*)(lds + lo + 32768 + k * 8192), 16, 0, 0);    \
    }

    STAGE(0, 0);
    i32x4 av[4];
#pragma unroll
    for (int g = 0; g < 4; ++g)
        av[g] = __builtin_nontemporal_load((const i32x4*)(arow + 8 * g));
    __syncthreads();  // buf0 staged (compiler drains vmcnt)

    int cur = 0;
    for (int t = 0; t < 32; ++t) {
        const int tn = (t + 1) & 31;
        STAGE(tn, cur ^ 1);
        i32x4 nv[4];
#pragma unroll
        for (int g = 0; g < 4; ++g)
            nv[g] = __builtin_nontemporal_load((const i32x4*)(arow + tn * 64 + 8 * g));

        const char* bufA = lds + cur * 65536;
        const char* bufF = bufA + 32768;

        // QK^T: S^T[j][i] for (iq, js)
        f32x16 sacc;
#pragma unroll
        for (int r = 0; r < 16; ++r) sacc[r] = 0.f;
#pragma unroll
        for (int kt = 0; kt < 16; ++kt) {
            half8 afr = *(const half8*)(bufA + (js * 16 + kt) * 1024 + (lane << 4));
            sacc = __builtin_amdgcn_mfma_f32_32x32x16_f16(afr, bq[kt], sacc, 0, 0, 0);
        }
        // masked exp (|s|<1)
        float wv[16];
#pragma unroll
        for (int r = 0; r < 16; ++r) {
            float e = av[r >> 2][r & 3] ? __expf(sacc[r]) : 0.f;
            wv[r] = e;
            rden += e;
        }
        // pack W -> A-frags (validated R4 formulas)
        int pq[8], qq[8];
#pragma unroll
        for (int q = 0; q < 8; ++q) {
            fp16x2 pp = __builtin_amdgcn_cvt_pkrtz(wv[2 * q], wv[2 * q + 1]);
            pq[q] = __builtin_bit_cast(int, pp);
            qq[q] = __shfl_xor(pq[q], 32, 64);
        }
        i32x4 af0 = {h ? qq[2] : pq[0], h ? qq[3] : pq[1], h ? pq[2] : qq[0], h ? pq[3] : qq[1]};
        i32x4 af1 = {h ? qq[6] : pq[4], h ? qq[7] : pq[5], h ? pq[6] : qq[4], h ? pq[7] : qq[5]};
        half8 afA = __builtin_bit_cast(half8, af0);
        half8 afB = __builtin_bit_cast(half8, af1);

        // exchange W frags with js-partner (same iq)
        char* wl = lds + 131072 + w * 2048;
        *(i32x4*)(wl + (lane << 4)) = af0;
        *(i32x4*)(wl + 1024 + (lane << 4)) = af1;
        __syncthreads();  // barrier 1: W visible
        const char* pl = lds + 131072 + (iq * 2 + (js ^ 1)) * 2048;
        half8 pf0 = *(const half8*)(pl + (lane << 4));
        half8 pf1 = *(const half8*)(pl + 1024 + (lane << 4));
        // k-chunk order over the 64-j tile: js=0 owns chunks 0,1; js=1 owns 2,3
        half8 c0 = js ? pf0 : afA;
        half8 c1 = js ? pf1 : afB;
        half8 c2 = js ? afA : pf0;
        half8 c3 = js ? afB : pf1;

        // PV: wave covers d in [js*128, js*128+128), all 64 j of tile
#pragma unroll
        for (int fl = 0; fl < 4; ++fl) {
            const int fg = js * 4 + fl;
            half8 b0 = *(const half8*)(bufF + (0 * 16 + fg * 2 + 0) * 1024 + (lane << 4));
            acc[fl] = __builtin_amdgcn_mfma_f32_32x32x16_f16(c0, b0, acc[fl], 0, 0, 0);
            half8 b1 = *(const half8*)(bufF + (0 * 16 + fg * 2 + 1) * 1024 + (lane << 4));
            acc[fl] = __builtin_amdgcn_mfma_f32_32x32x16_f16(c1, b1, acc[fl], 0, 0, 0);
            half8 b2 = *(const half8*)(bufF + (1 * 16 + fg * 2 + 0) * 1024 + (lane << 4));
            acc[fl] = __builtin_amdgcn_mfma_f32_32x32x16_f16(c2, b2, acc[fl], 0, 0, 0);
            half8 b3 = *(const half8*)(bufF + (1 * 16 + fg * 2 + 1) * 1024 + (lane << 4));
            acc[fl] = __builtin_amdgcn_mfma_f32_32x32x16_f16(c3, b3, acc[fl], 0, 0, 0);
        }
#pragma unroll
        for (int g = 0; g < 4; ++g) av[g] = nv[g];
        __syncthreads();  // barrier 2: buf[cur] reads done; next stage landed
        cur ^= 1;
    }

    // den: lane il holds i-col il of iq's block
    rden += __shfl_xor(rden, 32, 64);
    if (lane < 32) atomicAdd(&den[ibase + iq * 32 + lane], rden);

    // output: each (i,d) owned by exactly one wave in this block; 4 j-quarter
    // blocks collide -> global atomics, coalesced over il (consecutive d)
#pragma unroll
    for (int fl = 0; fl < 4; ++fl) {
#pragma unroll
        for (int r = 0; r < 16; ++r) {
            int ir = (r & 3) + 8 * (r >> 2) + 4 * h;
            atomicAdd(&out[(size_t)(ibase + iq * 32 + ir) * DDIM + (js * 4 + fl) * 32 + il],
                      acc[fl][r]);
        }
    }
#undef STAGE
}

// ---- finalize: O[i][:] /= den[i] ------------------------------------------
__global__ void finalize_div(float* __restrict__ out, const float* __restrict__ den) {
    int row = blockIdx.x;
    out[(size_t)row * DDIM + threadIdx.x] /= den[row];
}

extern "C" void kernel_launch(void* const* d_in, const int* in_sizes, int n_in,
                              void* d_out, int out_size, void* d_ws, size_t ws_size,
                              hipStream_t stream) {
    const float* xi   = (const float*)d_in[0];
    const float* xj   = (const float*)d_in[1];
    const int*   adj  = (const int*)d_in[2];
    const float* beta = (const float*)d_in[3];
    float* out = (float*)d_out;
    char*  ws  = (char*)d_ws;

    _Float16* xi_s = (_Float16*)(ws);                // 4MB
    half8*    xjA  = (half8*)(ws + (4u << 20));      // 4MB
    half8*    xjF  = (half8*)(ws + (8u << 20));      // 4MB
    float*    den  = (float*)(ws + (12u << 20));     // 32KB

    hipFuncSetAttribute((const void*)attn_main,
                        hipFuncAttributeMaxDynamicSharedMemorySize, 147456);

    hipMemsetAsync(d_out, 0, (size_t)N_ROWS * DDIM * sizeof(float), stream);
    hipMemsetAsync(den, 0, (size_t)N_ROWS * sizeof(float), stream);

    prep_scale<<<N_ROWS / 4, 256, 0, stream>>>(xi, xi_s, beta);
    prep_xj<<<M_ROWS / 32, 256, 0, stream>>>(xj, xjA, xjF);
    attn_main<<<256, 512, 147456, stream>>>(xi_s, xjA, xjF, adj, out, den);
    finalize_div<<<N_ROWS, 256, 0, stream>>>(out, den);
}